// Round 14
// baseline (127.912 us; speedup 1.0000x reference)
//
#include <hip/hip_runtime.h>
#include <hip/hip_bf16.h>

// IntraCellularAttention: B=1024, D_INNER=4096, D_STATE=16, D_ATTN=16
// out[b,d,s] = h[b,d,s] + gate * sum_t attn[b,s,t] * h[b,d,t]
// attn[s,t] = softmax_t( (Q K^T)[s,t] * 0.25 ),  Q[s,a] = sum_d h[b,d,s] Wq[a,d]
//
// TWO batches per block (grid 512, 512 threads, launch_bounds(512,1)).
// Rationale (round-13 post-mortem): P1 is read-only, P3 is write-only; with
// one batch per block the two HBM directions serialize. Pipelining batch
// b1's H loads INTO P3(b0) -- reloading each H[2it] register pair right
// after its last use (residual add) -- overlaps b1's read stream with b0's
// write stream. P1'(b1) then runs from registers (no HBM reads).
// ROUND-12 LESSON kept: every H[it] has an arithmetic use in its P3
// (residual add) so the allocator keeps H in registers, and all H indices
// are compile-time constants (fully unrolled loops).

constexpr int DI = 4096;
constexpr int DS = 16;
constexpr int NW = 8;                       // waves per block

typedef __attribute__((ext_vector_type(8))) short bf16x8;
typedef __attribute__((ext_vector_type(4))) float f32x4;

static __device__ __forceinline__ short f2bf(float x) {
    union { __hip_bfloat16 h; short s; } u;
    u.h = __float2bfloat16(x);
    return u.s;
}

__global__ __launch_bounds__(512, 1) void ica_fused(
    const float* __restrict__ h,
    const float* __restrict__ Wq,
    const float* __restrict__ Wk,
    const float* __restrict__ gate,
    float* __restrict__ out)
{
    const int b0   = blockIdx.x * 2;
    const int b1   = b0 + 1;
    const int tid  = threadIdx.x;
    const int lane = tid & 63;
    const int wv   = tid >> 6;              // 0..7

    const float* __restrict__ hbase0 = h   + (size_t)b0 * (DI * DS);
    const float* __restrict__ hbase1 = h   + (size_t)b1 * (DI * DS);
    float*       __restrict__ obase0 = out + (size_t)b0 * (DI * DS);
    float*       __restrict__ obase1 = out + (size_t)b1 * (DI * DS);

    __shared__ float st[NW][32][20];        // per-wave transpose tile
    __shared__ float qp[NW][16][20];        // Q partials [w][s][a]
    __shared__ float kp[NW][16][20];        // K partials
    __shared__ float Qs[16][20];
    __shared__ float Ks[16][20];
    __shared__ float Ms[16][20];            // Ms[s][t] = g * attn[s][t]

    const int sa   = lane & 15;             // A/B row index and MFMA col
    const int kb   = lane >> 4;             // k-subblock 0..3
    const int row  = lane >> 2;             // coalesced-layout row (0..15)
    const int quad = lane & 3;              // float4 slot within row

    const float4* __restrict__ h4_0 = (const float4*)hbase0 + (size_t)wv * 2048;
    const float4* __restrict__ h4_1 = (const float4*)hbase1 + (size_t)wv * 2048;
    const int d0w = wv * 512;

    const float* __restrict__ wqb = Wq + (size_t)sa * DI;
    const float* __restrict__ wkb = Wk + (size_t)sa * DI;
    const float g = gate[0];

    float4 H[32];                           // register-resident h slice
    float4 WQ0[3], WQ1[3], WK0[3], WK1[3];  // 3-slot W landing (L2)

#define LD_W(C, SL) do {                                                    \
        const int db_ = d0w + (C) * 32 + kb * 8;                            \
        WQ0[SL] = *(const float4*)(wqb + db_);                              \
        WQ1[SL] = *(const float4*)(wqb + db_ + 4);                          \
        WK0[SL] = *(const float4*)(wkb + db_);                              \
        WK1[SL] = *(const float4*)(wkb + db_ + 4);                          \
    } while (0)

#define LD_H0(C) do {                                                       \
        H[2*(C)]   = h4_0[(2*(C)) * 64 + lane];                             \
        H[2*(C)+1] = h4_0[(2*(C)+1) * 64 + lane];                           \
    } while (0)

    // ======================= P1(b0): H loads + W + MFMA ===================
    {
        f32x4 accQ = {0.f, 0.f, 0.f, 0.f};
        f32x4 accK = {0.f, 0.f, 0.f, 0.f};

        LD_H0(0); LD_W(0, 0);
        LD_H0(1); LD_W(1, 1);
        LD_H0(2); LD_W(2, 2);

        #pragma unroll
        for (int c = 0; c < 16; ++c) {
            const int sl = c % 3;
            *(float4*)&st[wv][row][quad * 4]      = H[2*c];
            *(float4*)&st[wv][row + 16][quad * 4] = H[2*c + 1];

            bf16x8 bq, bk;
            bq[0] = f2bf(WQ0[sl].x); bq[1] = f2bf(WQ0[sl].y);
            bq[2] = f2bf(WQ0[sl].z); bq[3] = f2bf(WQ0[sl].w);
            bq[4] = f2bf(WQ1[sl].x); bq[5] = f2bf(WQ1[sl].y);
            bq[6] = f2bf(WQ1[sl].z); bq[7] = f2bf(WQ1[sl].w);
            bk[0] = f2bf(WK0[sl].x); bk[1] = f2bf(WK0[sl].y);
            bk[2] = f2bf(WK0[sl].z); bk[3] = f2bf(WK0[sl].w);
            bk[4] = f2bf(WK1[sl].x); bk[5] = f2bf(WK1[sl].y);
            bk[6] = f2bf(WK1[sl].z); bk[7] = f2bf(WK1[sl].w);

            __builtin_amdgcn_wave_barrier();   // staging done before A reads

            if (c + 3 < 16) { LD_H0(c + 3); LD_W(c + 3, sl); }

            bf16x8 af;
            #pragma unroll
            for (int i = 0; i < 8; ++i)
                af[i] = f2bf(st[wv][kb * 8 + i][sa]);

            accQ = __builtin_amdgcn_mfma_f32_16x16x32_bf16(af, bq, accQ, 0, 0, 0);
            accK = __builtin_amdgcn_mfma_f32_16x16x32_bf16(af, bk, accK, 0, 0, 0);
            __builtin_amdgcn_wave_barrier();   // tile reads done before re-stage
        }

        #pragma unroll
        for (int r = 0; r < 4; ++r) {
            qp[wv][kb * 4 + r][sa] = accQ[r];
            kp[wv][kb * 4 + r][sa] = accK[r];
        }
    }
    __syncthreads();

#define REDUCE_AND_SOFTMAX() do {                                           \
        {                                                                   \
            const int idx = tid & 255;                                      \
            const int s2 = idx >> 4, a2 = idx & 15;                         \
            if (tid < 256) {                                                \
                float q = 0.f;                                              \
                _Pragma("unroll")                                           \
                for (int w = 0; w < NW; ++w) q += qp[w][s2][a2];            \
                Qs[s2][a2] = q;                                             \
            } else {                                                        \
                float k = 0.f;                                              \
                _Pragma("unroll")                                           \
                for (int w = 0; w < NW; ++w) k += kp[w][s2][a2];            \
                Ks[s2][a2] = k;                                             \
            }                                                               \
        }                                                                   \
        __syncthreads();                                                    \
        if (tid < 256) {                                                    \
            const int ss = tid >> 4;                                        \
            const int tt = tid & 15;                                        \
            float sc = 0.f;                                                 \
            _Pragma("unroll")                                               \
            for (int a4 = 0; a4 < 16; a4 += 4) {                            \
                float4 qv = *(const float4*)&Qs[ss][a4];                    \
                float4 kv = *(const float4*)&Ks[tt][a4];                    \
                sc = fmaf(qv.x, kv.x, sc);                                  \
                sc = fmaf(qv.y, kv.y, sc);                                  \
                sc = fmaf(qv.z, kv.z, sc);                                  \
                sc = fmaf(qv.w, kv.w, sc);                                  \
            }                                                               \
            sc *= 0.25f;                                                    \
            float m = sc;                                                   \
            _Pragma("unroll")                                               \
            for (int o = 8; o > 0; o >>= 1) m = fmaxf(m, __shfl_xor(m, o, 16)); \
            float e = __expf(sc - m);                                       \
            float sm = e;                                                   \
            _Pragma("unroll")                                               \
            for (int o = 8; o > 0; o >>= 1) sm += __shfl_xor(sm, o, 16);    \
            Ms[ss][tt] = g * (e / sm);                                      \
        }                                                                   \
        __syncthreads();                                                    \
    } while (0)

#define HOIST_BFRAG(BF) do {                                                \
        BF[0]=0; BF[1]=0; BF[2]=0; BF[3]=0;                                 \
        BF[4]=0; BF[5]=0; BF[6]=0; BF[7]=0;                                 \
        if (kb < 2) {                                                       \
            const float* mp = &Ms[sa][kb * 8];                              \
            float4 m0 = *(const float4*)mp;                                 \
            float4 m1 = *(const float4*)(mp + 4);                           \
            BF[0] = f2bf(m0.x); BF[1] = f2bf(m0.y);                         \
            BF[2] = f2bf(m0.z); BF[3] = f2bf(m0.w);                         \
            BF[4] = f2bf(m1.x); BF[5] = f2bf(m1.y);                         \
            BF[6] = f2bf(m1.z); BF[7] = f2bf(m1.w);                         \
        }                                                                   \
    } while (0)

    // P3 tile body: stage 2 tiles, MFMA, transpose-back, residual, NT store
#define P3_BODY(IT, BF, OBASE, PREFETCH_B1)                                 \
    {                                                                       \
        float (* __restrict__ stw)[20] = st[wv];                            \
        *(float4*)&stw[row][quad * 4]      = H[2*(IT)];                     \
        *(float4*)&stw[row + 16][quad * 4] = H[2*(IT) + 1];                 \
        __builtin_amdgcn_wave_barrier();                                    \
        const float* apA = &stw[sa][(kb & 1) * 8];                          \
        const float* apB = &stw[16 + sa][(kb & 1) * 8];                     \
        float4 aA0 = *(const float4*)apA;                                   \
        float4 aA1 = *(const float4*)(apA + 4);                             \
        float4 aB0 = *(const float4*)apB;                                   \
        float4 aB1 = *(const float4*)(apB + 4);                             \
        if (kb >= 2) {                                                      \
            aA0 = make_float4(0.f,0.f,0.f,0.f);                             \
            aA1 = make_float4(0.f,0.f,0.f,0.f);                             \
            aB0 = make_float4(0.f,0.f,0.f,0.f);                             \
            aB1 = make_float4(0.f,0.f,0.f,0.f);                             \
        }                                                                   \
        bf16x8 afA, afB;                                                    \
        afA[0]=f2bf(aA0.x); afA[1]=f2bf(aA0.y);                             \
        afA[2]=f2bf(aA0.z); afA[3]=f2bf(aA0.w);                             \
        afA[4]=f2bf(aA1.x); afA[5]=f2bf(aA1.y);                             \
        afA[6]=f2bf(aA1.z); afA[7]=f2bf(aA1.w);                             \
        afB[0]=f2bf(aB0.x); afB[1]=f2bf(aB0.y);                             \
        afB[2]=f2bf(aB0.z); afB[3]=f2bf(aB0.w);                             \
        afB[4]=f2bf(aB1.x); afB[5]=f2bf(aB1.y);                             \
        afB[6]=f2bf(aB1.z); afB[7]=f2bf(aB1.w);                             \
        f32x4 accA = {0.f,0.f,0.f,0.f};                                     \
        f32x4 accB = {0.f,0.f,0.f,0.f};                                     \
        accA = __builtin_amdgcn_mfma_f32_16x16x32_bf16(afA, BF, accA,0,0,0);\
        accB = __builtin_amdgcn_mfma_f32_16x16x32_bf16(afB, BF, accB,0,0,0);\
        __builtin_amdgcn_wave_barrier();                                    \
        _Pragma("unroll")                                                   \
        for (int r = 0; r < 4; ++r) {                                       \
            stw[kb * 4 + r][sa]      = accA[r];                             \
            stw[16 + kb * 4 + r][sa] = accB[r];                             \
        }                                                                   \
        __builtin_amdgcn_wave_barrier();                                    \
        float4 pvA = *(const float4*)&stw[row][quad * 4];                   \
        float4 pvB = *(const float4*)&stw[row + 16][quad * 4];              \
        f32x4 oA, oB;                                                       \
        oA[0] = H[2*(IT)].x + pvA.x;   oA[1] = H[2*(IT)].y + pvA.y;         \
        oA[2] = H[2*(IT)].z + pvA.z;   oA[3] = H[2*(IT)].w + pvA.w;         \
        oB[0] = H[2*(IT)+1].x + pvB.x; oB[1] = H[2*(IT)+1].y + pvB.y;       \
        oB[2] = H[2*(IT)+1].z + pvB.z; oB[3] = H[2*(IT)+1].w + pvB.w;       \
        const size_t orowA = (size_t)(d0w + (2*(IT))   * 16 + row) * DS + quad * 4; \
        const size_t orowB = (size_t)(d0w + (2*(IT)+1) * 16 + row) * DS + quad * 4; \
        __builtin_nontemporal_store(oA, (f32x4*)((OBASE) + orowA));         \
        __builtin_nontemporal_store(oB, (f32x4*)((OBASE) + orowB));         \
        if (PREFETCH_B1) {      /* reload freed H regs with batch b1 */     \
            H[2*(IT)]   = h4_1[(2*(IT)) * 64 + lane];                       \
            H[2*(IT)+1] = h4_1[(2*(IT)+1) * 64 + lane];                     \
        }                                                                   \
        __builtin_amdgcn_wave_barrier();                                    \
    }

    REDUCE_AND_SOFTMAX();                   // -> Ms(b0)

    // ======================= P3(b0) + b1 H prefetch =======================
    {
        bf16x8 bf0;
        HOIST_BFRAG(bf0);
        #pragma unroll
        for (int it = 0; it < 16; ++it)
            P3_BODY(it, bf0, obase0, 1);
    }

    // ======================= P1'(b1): H already resident ==================
    {
        f32x4 accQ = {0.f, 0.f, 0.f, 0.f};
        f32x4 accK = {0.f, 0.f, 0.f, 0.f};

        LD_W(0, 0);
        LD_W(1, 1);
        LD_W(2, 2);

        #pragma unroll
        for (int c = 0; c < 16; ++c) {
            const int sl = c % 3;
            *(float4*)&st[wv][row][quad * 4]      = H[2*c];
            *(float4*)&st[wv][row + 16][quad * 4] = H[2*c + 1];

            bf16x8 bq, bk;
            bq[0] = f2bf(WQ0[sl].x); bq[1] = f2bf(WQ0[sl].y);
            bq[2] = f2bf(WQ0[sl].z); bq[3] = f2bf(WQ0[sl].w);
            bq[4] = f2bf(WQ1[sl].x); bq[5] = f2bf(WQ1[sl].y);
            bq[6] = f2bf(WQ1[sl].z); bq[7] = f2bf(WQ1[sl].w);
            bk[0] = f2bf(WK0[sl].x); bk[1] = f2bf(WK0[sl].y);
            bk[2] = f2bf(WK0[sl].z); bk[3] = f2bf(WK0[sl].w);
            bk[4] = f2bf(WK1[sl].x); bk[5] = f2bf(WK1[sl].y);
            bk[6] = f2bf(WK1[sl].z); bk[7] = f2bf(WK1[sl].w);

            __builtin_amdgcn_wave_barrier();

            if (c + 3 < 16) LD_W(c + 3, sl);

            bf16x8 af;
            #pragma unroll
            for (int i = 0; i < 8; ++i)
                af[i] = f2bf(st[wv][kb * 8 + i][sa]);

            accQ = __builtin_amdgcn_mfma_f32_16x16x32_bf16(af, bq, accQ, 0, 0, 0);
            accK = __builtin_amdgcn_mfma_f32_16x16x32_bf16(af, bk, accK, 0, 0, 0);
            __builtin_amdgcn_wave_barrier();
        }

        #pragma unroll
        for (int r = 0; r < 4; ++r) {
            qp[wv][kb * 4 + r][sa] = accQ[r];
            kp[wv][kb * 4 + r][sa] = accK[r];
        }
    }
    __syncthreads();

    REDUCE_AND_SOFTMAX();                   // -> Ms(b1)

    // ======================= P3(b1): no prefetch ==========================
    {
        bf16x8 bf1;
        HOIST_BFRAG(bf1);
        #pragma unroll
        for (int it = 0; it < 16; ++it)
            P3_BODY(it, bf1, obase1, 0);
    }

#undef LD_W
#undef LD_H0
#undef REDUCE_AND_SOFTMAX
#undef HOIST_BFRAG
#undef P3_BODY
}

extern "C" void kernel_launch(void* const* d_in, const int* in_sizes, int n_in,
                              void* d_out, int out_size, void* d_ws, size_t ws_size,
                              hipStream_t stream) {
    const float* h    = (const float*)d_in[0];
    const float* Wq   = (const float*)d_in[1];
    const float* Wk   = (const float*)d_in[2];
    const float* gate = (const float*)d_in[3];
    float* out = (float*)d_out;
    (void)in_sizes; (void)n_in; (void)out_size; (void)d_ws; (void)ws_size;

    ica_fused<<<512, 512, 0, stream>>>(h, Wq, Wk, gate, out);
}

// Round 15
// 118.429 us; speedup vs baseline: 1.0801x; 1.0801x over previous
//
#include <hip/hip_runtime.h>
#include <hip/hip_bf16.h>

// IntraCellularAttention: B=1024, D_INNER=4096, D_STATE=16, D_ATTN=16
// out[b,d,s] = h[b,d,s] + gate * sum_t attn[b,s,t] * h[b,d,t]
// attn[s,t] = softmax_t( (Q K^T)[s,t] * 0.25 ),  Q[s,a] = sum_d h[b,d,s] Wq[a,d]
//
// FINAL (round-11 structure, best measured 115.7us = 73% of the pure-copy
// BW ceiling for the 530MB traffic floor).
// Register-resident h: 512 threads (8 waves), 1 block/batch, grid 1024.
// Each lane holds 32 float4 of h loaded ONCE, fully coalesced, 3-chunk
// lookahead. launch_bounds(512,1); VGPR 112 -> 2 blocks/CU co-resident,
// which naturally overlaps one block's P1 reads with the neighbor's P3
// writes (explicit intra-block pipelining regressed, round 14).
// Lessons encoded:
//  - H[] stays in registers only because each H[it] has an arithmetic use
//    in P3 (residual add); LDS-write-only liveness -> full spill (r12).
//  - W slot must be consumed to bf16 BEFORE the lookahead reload (r10).
//  - All loads/stores fully coalesced float4; strided dword loads pin
//    effective BW at ~50% (r8 -> r9).
//  - launch_bounds 2nd arg > 1 at 512 threads caps VGPR -> spills (r6/r7).

constexpr int DI = 4096;
constexpr int DS = 16;
constexpr int NW = 8;                       // waves per block

typedef __attribute__((ext_vector_type(8))) short bf16x8;
typedef __attribute__((ext_vector_type(4))) float f32x4;

static __device__ __forceinline__ short f2bf(float x) {
    union { __hip_bfloat16 h; short s; } u;
    u.h = __float2bfloat16(x);
    return u.s;
}

__global__ __launch_bounds__(512, 1) void ica_fused(
    const float* __restrict__ h,
    const float* __restrict__ Wq,
    const float* __restrict__ Wk,
    const float* __restrict__ gate,
    float* __restrict__ out)
{
    const int b    = blockIdx.x;
    const int tid  = threadIdx.x;
    const int lane = tid & 63;
    const int wv   = tid >> 6;              // 0..7

    const float* __restrict__ hbase = h   + (size_t)b * (DI * DS);
    float*       __restrict__ obase = out + (size_t)b * (DI * DS);

    __shared__ float st[NW][32][20];        // per-wave transpose tile
    __shared__ float qp[NW][16][20];        // Q partials [w][s][a]
    __shared__ float kp[NW][16][20];        // K partials
    __shared__ float Qs[16][20];
    __shared__ float Ks[16][20];
    __shared__ float Ms[16][20];            // Ms[s][t] = g * attn[s][t]

    const int sa   = lane & 15;             // A/B row index and MFMA col
    const int kb   = lane >> 4;             // k-subblock 0..3
    const int row  = lane >> 2;             // coalesced-layout row (0..15)
    const int quad = lane & 3;              // float4 slot within row

    // wave's 512 rows as 2048 float4; lane's j-th f4 = row j*16+row, quad
    const float4* __restrict__ h4 = (const float4*)hbase + (size_t)wv * 2048;
    const int d0w = wv * 512;

    float4 H[32];                           // register-resident h slice

    // ---------------- Phase 1: Q,K via MFMA, regs->LDS transpose ----------
    {
        const float* __restrict__ wqb = Wq + (size_t)sa * DI;
        const float* __restrict__ wkb = Wk + (size_t)sa * DI;

        f32x4 accQ = {0.f, 0.f, 0.f, 0.f};
        f32x4 accK = {0.f, 0.f, 0.f, 0.f};

        float4 WQ0[3], WQ1[3], WK0[3], WK1[3];   // 3-slot W landing (L2)

#define LD_CHUNK(C, SL) do {                                                \
        H[2*(C)]   = h4[(2*(C)) * 64 + lane];                               \
        H[2*(C)+1] = h4[(2*(C)+1) * 64 + lane];                             \
        const int db_ = d0w + (C) * 32 + kb * 8;                            \
        WQ0[SL] = *(const float4*)(wqb + db_);                              \
        WQ1[SL] = *(const float4*)(wqb + db_ + 4);                          \
        WK0[SL] = *(const float4*)(wkb + db_);                              \
        WK1[SL] = *(const float4*)(wkb + db_ + 4);                          \
    } while (0)

        LD_CHUNK(0, 0);
        LD_CHUNK(1, 1);
        LD_CHUNK(2, 2);

        #pragma unroll
        for (int c = 0; c < 16; ++c) {
            const int sl = c % 3;
            // stage chunk c (32 rows) into the wave tile
            *(float4*)&st[wv][row][quad * 4]      = H[2*c];
            *(float4*)&st[wv][row + 16][quad * 4] = H[2*c + 1];

            // consume this slot's W into bf16 regs BEFORE the lookahead
            // overwrites it (lookahead distance == slot count)
            bf16x8 bq, bk;
            bq[0] = f2bf(WQ0[sl].x); bq[1] = f2bf(WQ0[sl].y);
            bq[2] = f2bf(WQ0[sl].z); bq[3] = f2bf(WQ0[sl].w);
            bq[4] = f2bf(WQ1[sl].x); bq[5] = f2bf(WQ1[sl].y);
            bq[6] = f2bf(WQ1[sl].z); bq[7] = f2bf(WQ1[sl].w);
            bk[0] = f2bf(WK0[sl].x); bk[1] = f2bf(WK0[sl].y);
            bk[2] = f2bf(WK0[sl].z); bk[3] = f2bf(WK0[sl].w);
            bk[4] = f2bf(WK1[sl].x); bk[5] = f2bf(WK1[sl].y);
            bk[6] = f2bf(WK1[sl].z); bk[7] = f2bf(WK1[sl].w);

            __builtin_amdgcn_wave_barrier();   // staging done before A reads

            // issue lookahead chunk into the now-free slot
            if (c + 3 < 16) LD_CHUNK(c + 3, sl);

            // A-frag: S[sa][d] = h[d][sa], d = chunk-local kb*8+i
            bf16x8 af;
            #pragma unroll
            for (int i = 0; i < 8; ++i)
                af[i] = f2bf(st[wv][kb * 8 + i][sa]);

            accQ = __builtin_amdgcn_mfma_f32_16x16x32_bf16(af, bq, accQ, 0, 0, 0);
            accK = __builtin_amdgcn_mfma_f32_16x16x32_bf16(af, bk, accK, 0, 0, 0);
            __builtin_amdgcn_wave_barrier();   // tile reads done before re-stage
        }
#undef LD_CHUNK

        // D mapping (verified): col = lane&15 (=a), row = (lane>>4)*4+reg (=s)
        #pragma unroll
        for (int r = 0; r < 4; ++r) {
            qp[wv][kb * 4 + r][sa] = accQ[r];
            kp[wv][kb * 4 + r][sa] = accK[r];
        }
    }
    __syncthreads();

    // ---------------- reduce the 8 wave partials --------------------------
    {
        const int idx = tid & 255;
        const int s2 = idx >> 4, a2 = idx & 15;
        if (tid < 256) {
            float q = 0.f;
            #pragma unroll
            for (int w = 0; w < NW; ++w) q += qp[w][s2][a2];
            Qs[s2][a2] = q;
        } else {
            float k = 0.f;
            #pragma unroll
            for (int w = 0; w < NW; ++w) k += kp[w][s2][a2];
            Ks[s2][a2] = k;
        }
    }
    __syncthreads();

    // ---------------- Phase 2: scores + softmax + fold gate ---------------
    const float g = gate[0];
    if (tid < 256) {
        const int ss = tid >> 4;   // query slot
        const int tt = tid & 15;   // key slot
        float sc = 0.f;
        #pragma unroll
        for (int a4 = 0; a4 < 16; a4 += 4) {
            float4 qv = *(const float4*)&Qs[ss][a4];
            float4 kv = *(const float4*)&Ks[tt][a4];
            sc = fmaf(qv.x, kv.x, sc);
            sc = fmaf(qv.y, kv.y, sc);
            sc = fmaf(qv.z, kv.z, sc);
            sc = fmaf(qv.w, kv.w, sc);
        }
        sc *= 0.25f;  // D_ATTN^-0.5

        float m = sc;
        #pragma unroll
        for (int o = 8; o > 0; o >>= 1) m = fmaxf(m, __shfl_xor(m, o, 16));
        float e = __expf(sc - m);
        float sm = e;
        #pragma unroll
        for (int o = 8; o > 0; o >>= 1) sm += __shfl_xor(sm, o, 16);
        Ms[ss][tt] = g * (e / sm);
    }
    __syncthreads();

    // ---------------- Phase 3: PV from registers, zero global reads -------
    {
        float (* __restrict__ stw)[20] = st[wv];

        // hoisted B fragment: B[k=t][col=s] = Ms[s][t], zero for t>=16
        bf16x8 bfrag = {0, 0, 0, 0, 0, 0, 0, 0};
        if (kb < 2) {
            const float* mp = &Ms[sa][kb * 8];
            float4 m0 = *(const float4*)mp;
            float4 m1 = *(const float4*)(mp + 4);
            bfrag[0] = f2bf(m0.x); bfrag[1] = f2bf(m0.y);
            bfrag[2] = f2bf(m0.z); bfrag[3] = f2bf(m0.w);
            bfrag[4] = f2bf(m1.x); bfrag[5] = f2bf(m1.y);
            bfrag[6] = f2bf(m1.z); bfrag[7] = f2bf(m1.w);
        }

        #pragma unroll
        for (int it = 0; it < 32; ++it) {
            // stage tile from registers
            *(float4*)&stw[row][quad * 4] = H[it];
            __builtin_amdgcn_wave_barrier();

            // A-frag: tile[sa][(kb&1)*8 ..+7]; kb>=2 lanes carry K-padding 0
            const float* ap = &stw[sa][(kb & 1) * 8];
            float4 aa0 = *(const float4*)ap;
            float4 aa1 = *(const float4*)(ap + 4);
            if (kb >= 2) {
                aa0 = make_float4(0.f, 0.f, 0.f, 0.f);
                aa1 = make_float4(0.f, 0.f, 0.f, 0.f);
            }
            bf16x8 af;
            af[0] = f2bf(aa0.x); af[1] = f2bf(aa0.y);
            af[2] = f2bf(aa0.z); af[3] = f2bf(aa0.w);
            af[4] = f2bf(aa1.x); af[5] = f2bf(aa1.y);
            af[6] = f2bf(aa1.z); af[7] = f2bf(aa1.w);

            f32x4 acc = {0.f, 0.f, 0.f, 0.f};
            acc = __builtin_amdgcn_mfma_f32_16x16x32_bf16(af, bfrag, acc, 0, 0, 0);
            __builtin_amdgcn_wave_barrier();   // A reads done before transpose

            // transpose D (col sa, rows kb*4+r) back through the tile
            #pragma unroll
            for (int r = 0; r < 4; ++r)
                stw[kb * 4 + r][sa] = acc[r];
            __builtin_amdgcn_wave_barrier();

            float4 pv = *(const float4*)&stw[row][quad * 4];
            f32x4 o;
            o[0] = H[it].x + pv.x;
            o[1] = H[it].y + pv.y;
            o[2] = H[it].z + pv.z;
            o[3] = H[it].w + pv.w;
            const size_t orow = (size_t)(d0w + it * 16 + row) * DS + quad * 4;
            __builtin_nontemporal_store(o, (f32x4*)(obase + orow));
            __builtin_amdgcn_wave_barrier();   // pv reads done before next stage
        }
    }
}

extern "C" void kernel_launch(void* const* d_in, const int* in_sizes, int n_in,
                              void* d_out, int out_size, void* d_ws, size_t ws_size,
                              hipStream_t stream) {
    const float* h    = (const float*)d_in[0];
    const float* Wq   = (const float*)d_in[1];
    const float* Wk   = (const float*)d_in[2];
    const float* gate = (const float*)d_in[3];
    float* out = (float*)d_out;
    (void)in_sizes; (void)n_in; (void)out_size; (void)d_ws; (void)ws_size;

    ica_fused<<<1024, 512, 0, stream>>>(h, Wq, Wk, gate, out);
}